// Round 7
// baseline (97.972 us; speedup 1.0000x reference)
//
#include <hip/hip_runtime.h>
#include <hip/hip_bf16.h>

// SEQ=512, BATCH=64, DIM=512, MAXLEN=512, E=655360
// out[b][u][s] = edge(b,u,s) ? exp(scale) / (T_e + 1e-10*(T-T_e)) : 0  (max cancels)
// scale[s,b,m] = sum_d M[s,b,d] * W[m,d]
//
// Primary path (needs ws >= ~36.2 MB):
//   prep: M,W -> bf16 + edge bitmap (one kernel)
//   fused_attn_p: block = (b, m-tile 64) x s=512, 8 waves (one 64-s band each).
//     A resident in LDS (64 KB, swizzled); B = wave-private bands DMA'd 3-deep
//     via global_load_lds with counted vmcnt; ZERO barriers in K-loop.
// Fallback path (round-6 kernel) if ws_size too small.

#define SEQ 512
#define BATCH 64
#define DIM 512
#define MAXLEN 512

typedef __attribute__((ext_vector_type(8))) __bf16 bf16x8;
typedef __attribute__((ext_vector_type(4))) float f32x4;

__device__ __forceinline__ unsigned cvt_pk(float lo, float hi) {
    unsigned r;
    asm("v_cvt_pk_bf16_f32 %0, %1, %2" : "=v"(r) : "v"(lo), "v"(hi));
    return r;
}

__device__ __forceinline__ void gload16(const void* g, void* l) {
    __builtin_amdgcn_global_load_lds(
        (const __attribute__((address_space(1))) void*)g,
        (__attribute__((address_space(3))) void*)l, 16, 0, 0);
}

// ================= primary path =================

// blocks 0..8191: cvt M; 8192..10751: edge scatter; 10752..10879: cvt W
__global__ __launch_bounds__(256) void prep(const float* __restrict__ Mg,
                                            const float* __restrict__ Wg,
                                            const int* __restrict__ eb,
                                            const int* __restrict__ eu,
                                            const int* __restrict__ ev,
                                            unsigned short* __restrict__ Mbf,
                                            unsigned short* __restrict__ Wbf,
                                            unsigned* __restrict__ bits, int E) {
    int blk = blockIdx.x;
    if (blk < 8192) {
        size_t id = (size_t)blk * 256 + threadIdx.x;        // 2,097,152 x 8 floats
        const float4* s = (const float4*)Mg + id * 2;
        float4 a = s[0], c = s[1];
        uint4 o;
        o.x = cvt_pk(a.x, a.y); o.y = cvt_pk(a.z, a.w);
        o.z = cvt_pk(c.x, c.y); o.w = cvt_pk(c.z, c.w);
        ((uint4*)Mbf)[id] = o;
    } else if (blk < 10752) {
        int i = (blk - 8192) * 256 + threadIdx.x;
        if (i < E)
            atomicOr(&bits[(eb[i] * MAXLEN + eu[i]) * 16 + (ev[i] >> 5)],
                     1u << (ev[i] & 31));
    } else {
        size_t id = (size_t)(blk - 10752) * 256 + threadIdx.x;  // 32768 x 8 floats
        const float4* s = (const float4*)Wg + id * 2;
        float4 a = s[0], c = s[1];
        uint4 o;
        o.x = cvt_pk(a.x, a.y); o.y = cvt_pk(a.z, a.w);
        o.z = cvt_pk(c.x, c.y); o.w = cvt_pk(c.z, c.w);
        ((uint4*)Wbf)[id] = o;
    }
}

__global__ __launch_bounds__(512, 1) void fused_attn_p(
    const unsigned short* __restrict__ Mbf,
    const unsigned short* __restrict__ Wbf,
    const unsigned int* __restrict__ bitsG,
    float* __restrict__ out) {
    // LDS map (exactly 160 KiB):
    //   [0, 65536):  A 64 rows x 1024B bf16, chunk16 ^= (row&7)
    //   [65536, 163840): B 3 bufs x 8 waves x (64 rows x 64B), chunk ^= ((row>>1)&3)
    //   epilogue overlays: red (float2[512]) at +65536; stg [16][516] f32 at 0
    __shared__ __align__(16) char lds[163840];

    const int g = blockIdx.x;
    const int work = (g & 7) * 64 + (g >> 3);   // bijective [0,512): same-b on one XCD
    const int b  = work >> 3;
    const int m0 = (work & 7) * 64;

    const int t = threadIdx.x, lane = t & 63, wv = t >> 6;
    const int lg = lane >> 4, lc = lane & 15;

    // ---- B DMA per-lane source (swizzle folded into source chunk) ----
    const int srow = wv * 64 + (lane >> 2);                 // + q*16 rows
    const int cs   = (lane & 3) ^ ((lane >> 3) & 3);        // source chunk in 64B row
    const char* bsrc = (const char*)Mbf + ((size_t)srow * BATCH + b) * (DIM * 2) + cs * 16;
    char* const bband0 = lds + 65536 + wv * 4096;           // + p*32768 + q*1024

    // prologue: issue B(0),B(1),B(2)
#pragma unroll
    for (int p = 0; p < 3; ++p)
#pragma unroll
        for (int q = 0; q < 4; ++q)
            gload16(bsrc + ((size_t)q << 20) + p * 64, bband0 + p * 32768 + q * 1024);

    // ---- stage whole A tile (64 x 512 bf16), swizzled ----
    {
        const char* wb = (const char*)Wbf + (size_t)m0 * (DIM * 2);
        const int r = t >> 3;
#pragma unroll
        for (int i = 0; i < 8; ++i) {
            int ch  = (t & 7) * 8 + i;
            int csA = ch ^ (r & 7);
            uint4 v = *(const uint4*)(wb + (size_t)r * 1024 + csA * 16);
            *(uint4*)(lds + r * 1024 + ch * 16) = v;
        }
    }
    __syncthreads();   // A visible; prologue DMAs drained too (once, acceptable)

    f32x4 acc[4][4] = {};

#pragma unroll
    for (int ks = 0; ks < 16; ++ks) {
        if (ks <= 13)      asm volatile("s_waitcnt vmcnt(8)" ::: "memory");
        else if (ks == 14) asm volatile("s_waitcnt vmcnt(4)" ::: "memory");
        else               asm volatile("s_waitcnt vmcnt(0)" ::: "memory");

        const char* bb = lds + 65536 + (ks % 3) * 32768 + wv * 4096;
        bf16x8 af[4], bfr[4];
#pragma unroll
        for (int i = 0; i < 4; ++i) {
            int r  = i * 16 + lc;
            int ch = (ks * 4 + lg) ^ (lc & 7);
            af[i] = *(const bf16x8*)(lds + r * 1024 + ch * 16);
        }
#pragma unroll
        for (int j = 0; j < 4; ++j) {
            int r  = j * 16 + lc;
            int ch = lg ^ ((lc >> 1) & 3);
            bfr[j] = *(const bf16x8*)(bb + r * 64 + ch * 16);
        }
#pragma unroll
        for (int i = 0; i < 4; ++i)
#pragma unroll
            for (int j = 0; j < 4; ++j)
                acc[i][j] = __builtin_amdgcn_mfma_f32_16x16x32_bf16(af[i], bfr[j], acc[i][j], 0, 0, 0);

        if (ks + 3 < 16) {
            __builtin_amdgcn_sched_barrier(0);   // keep issues after this step's reads
#pragma unroll
            for (int q = 0; q < 4; ++q)
                gload16(bsrc + ((size_t)q << 20) + (ks + 3) * 64,
                        bband0 + (ks % 3) * 32768 + q * 1024);
        }
    }

    __syncthreads();   // all waves done with B region before red overlay

    float2* const red = (float2*)(lds + 65536);
    // ---- pass 1: exp + per-wave (T,Te) partials ----
#pragma unroll
    for (int i = 0; i < 4; ++i) {
#pragma unroll
        for (int r = 0; r < 4; ++r) {
            const int m = i * 16 + lg * 4 + r;
            const uint2 wbt = *(const uint2*)(bitsG + (size_t)(b * MAXLEN + m0 + m) * 16 + wv * 2);
            float T = 0.f, Te = 0.f;
#pragma unroll
            for (int j = 0; j < 4; ++j) {
                float e = __expf(acc[i][j][r]);
                acc[i][j][r] = e;
                unsigned word = (j & 2) ? wbt.y : wbt.x;
                float bit = (float)((word >> ((j & 1) * 16 + lc)) & 1u);
                T += e; Te += e * bit;
            }
#pragma unroll
            for (int off = 1; off < 16; off <<= 1) {
                T  += __shfl_xor(T, off);
                Te += __shfl_xor(Te, off);
            }
            if (lc == 0) red[m * 8 + wv] = make_float2(T, Te);
        }
    }
    __syncthreads();

    // ---- pass 2: masked scale -> LDS transpose -> coalesced full-line stores ----
    float* const stg = (float*)lds;
    for (int i = 0; i < 4; ++i) {
        float inv[4];
        uint2 wbt2[4];
#pragma unroll
        for (int r = 0; r < 4; ++r) {
            const int m = i * 16 + lg * 4 + r;
            float T = 0.f, Te = 0.f;
#pragma unroll
            for (int q = 0; q < 8; ++q) {
                float2 p = red[m * 8 + q];
                T += p.x; Te += p.y;
            }
            inv[r] = 1.0f / (Te + 1e-10f * (T - Te));
            wbt2[r] = *(const uint2*)(bitsG + (size_t)(b * MAXLEN + m0 + m) * 16 + wv * 2);
        }
#pragma unroll
        for (int r = 0; r < 4; ++r) {
#pragma unroll
            for (int j = 0; j < 4; ++j) {
                unsigned word = (j & 2) ? wbt2[r].y : wbt2[r].x;
                unsigned bit = (word >> ((j & 1) * 16 + lc)) & 1u;
                stg[(lg * 4 + r) * 516 + wv * 64 + j * 16 + lc] =
                    bit ? acc[i][j][r] * inv[r] : 0.0f;
            }
        }
        __syncthreads();
#pragma unroll
        for (int it = 0; it < 4; ++it) {
            int f = it * 512 + t;
            int ml = f >> 7;
            int s4 = (f & 127) * 4;
            float4 v = *(const float4*)(stg + ml * 516 + s4);
            *(float4*)(out + ((size_t)(b * MAXLEN + m0 + i * 16 + ml)) * SEQ + s4) = v;
        }
        __syncthreads();
    }
}

// ================= fallback path (round-6, known-correct) =================

__global__ __launch_bounds__(256) void edge_scatter(const int* __restrict__ eb,
                                                    const int* __restrict__ eu,
                                                    const int* __restrict__ ev,
                                                    unsigned int* __restrict__ bits,
                                                    int E) {
    int i = blockIdx.x * 256 + threadIdx.x;
    if (i < E) {
        int b = eb[i], u = eu[i], v = ev[i];
        atomicOr(&bits[(b * MAXLEN + u) * 16 + (v >> 5)], 1u << (v & 31));
    }
}

__global__ __launch_bounds__(256) void cvt_w(const float* __restrict__ src,
                                             unsigned short* __restrict__ dst) {
    int i = blockIdx.x * 256 + threadIdx.x;
    const float4* s = (const float4*)src + (size_t)i * 2;
    float4 a = s[0], c = s[1];
    uint4 o;
    o.x = cvt_pk(a.x, a.y); o.y = cvt_pk(a.z, a.w);
    o.z = cvt_pk(c.x, c.y); o.w = cvt_pk(c.z, c.w);
    ((uint4*)dst)[i] = o;
}

__global__ __launch_bounds__(512, 4) void fused_attn(
    const float* __restrict__ Mg,
    const unsigned short* __restrict__ Wbf,
    const unsigned int* __restrict__ bitsG,
    float* __restrict__ out) {
    __shared__ __align__(16) char lds[81920];
    char* bufB  = lds;
    char* curA  = lds + 65536;
    char* nxtA  = lds + 69632;
    float2* red = (float2*)(lds + 73728);
    unsigned* bitsL = (unsigned*)(lds + 77824);
    float* stg = (float*)lds;

    const int g = blockIdx.x;
    const int work = (g & 7) * 64 + (g >> 3);
    const int b  = work >> 3;
    const int m0 = (work & 7) * 64;

    const int t = threadIdx.x;
    const int lane = t & 63;
    const int wv = t >> 6;
    const int lg = lane >> 4;
    const int lc = lane & 15;

    if (t < 256)
        ((uint4*)bitsL)[t] = ((const uint4*)(bitsG + (size_t)(b * MAXLEN + m0) * 16))[t];

    const int brs = lane >> 3;
    const int bc  = (lane & 7) ^ brs;
    const int ars = lane >> 2;
    const int ac  = (lane & 3) ^ ((ars >> 2) & 3);

    const char* const MgB = (const char*)Mg + (size_t)b * DIM * 4;
    const char* const WbB = (const char*)Wbf + (size_t)m0 * DIM * 2;

    f32x4 acc[4][4] = {};

    if (wv < 4)
        gload16(WbB + (size_t)(wv * 16 + ars) * (DIM * 2) + ac * 16, curA + wv * 16 * 64);
    __syncthreads();

#pragma unroll 2
    for (int ks = 0; ks < 16; ++ks) {
        const int kb = ks * 128;
#pragma unroll
        for (int q = 0; q < 8; ++q) {
            int r = wv * 64 + q * 8 + brs;
            gload16(MgB + (size_t)r * (BATCH * DIM * 4) + kb + bc * 16,
                    bufB + (wv * 64 + q * 8) * 128);
        }
        const bool pfA = (ks < 15) && (wv < 4);
        if (pfA)
            gload16(WbB + (size_t)(wv * 16 + ars) * (DIM * 2) + (ks + 1) * 64 + ac * 16,
                    nxtA + wv * 16 * 64);
        if (pfA) asm volatile("s_waitcnt vmcnt(1)" ::: "memory");
        else     asm volatile("s_waitcnt vmcnt(0)" ::: "memory");

        const int fxr = (lc >> 2) & 3;
        bf16x8 af[4];
#pragma unroll
        for (int i = 0; i < 4; ++i)
            af[i] = *(const bf16x8*)(curA + (i * 16 + lc) * 64 + ((lg ^ fxr) * 16));
        const int bxr = lc & 7;
        bf16x8 bfr[4];
#pragma unroll
        for (int j = 0; j < 4; ++j) {
            const char* rowp = bufB + (wv * 64 + j * 16 + lc) * 128;
            f32x4 x = *(const f32x4*)(rowp + (((2 * lg) ^ bxr) * 16));
            f32x4 y = *(const f32x4*)(rowp + (((2 * lg + 1) ^ bxr) * 16));
            uint4 pk;
            pk.x = cvt_pk(x[0], x[1]); pk.y = cvt_pk(x[2], x[3]);
            pk.z = cvt_pk(y[0], y[1]); pk.w = cvt_pk(y[2], y[3]);
            bfr[j] = __builtin_bit_cast(bf16x8, pk);
        }
#pragma unroll
        for (int i = 0; i < 4; ++i)
#pragma unroll
            for (int j = 0; j < 4; ++j)
                acc[i][j] = __builtin_amdgcn_mfma_f32_16x16x32_bf16(af[i], bfr[j], acc[i][j], 0, 0, 0);
        __syncthreads();
        { char* tmp = curA; curA = nxtA; nxtA = tmp; }
    }

#pragma unroll
    for (int i = 0; i < 4; ++i) {
#pragma unroll
        for (int r = 0; r < 4; ++r) {
            const int m = i * 16 + lg * 4 + r;
            const uint2 wbt = *(const uint2*)(bitsL + m * 16 + wv * 2);
            float T = 0.f, Te = 0.f;
#pragma unroll
            for (int j = 0; j < 4; ++j) {
                float e = __expf(acc[i][j][r]);
                acc[i][j][r] = e;
                unsigned word = (j & 2) ? wbt.y : wbt.x;
                float bit = (float)((word >> ((j & 1) * 16 + lc)) & 1u);
                T += e; Te += e * bit;
            }
#pragma unroll
            for (int off = 1; off < 16; off <<= 1) {
                T  += __shfl_xor(T, off);
                Te += __shfl_xor(Te, off);
            }
            if (lc == 0) red[m * 8 + wv] = make_float2(T, Te);
        }
    }
    __syncthreads();

    for (int i = 0; i < 4; ++i) {
        float inv[4];
        uint2 wbt2[4];
#pragma unroll
        for (int r = 0; r < 4; ++r) {
            const int m = i * 16 + lg * 4 + r;
            float T = 0.f, Te = 0.f;
#pragma unroll
            for (int q = 0; q < 8; ++q) {
                float2 p = red[m * 8 + q];
                T += p.x; Te += p.y;
            }
            inv[r] = 1.0f / (Te + 1e-10f * (T - Te));
            wbt2[r] = *(const uint2*)(bitsL + m * 16 + wv * 2);
        }
#pragma unroll
        for (int r = 0; r < 4; ++r) {
#pragma unroll
            for (int j = 0; j < 4; ++j) {
                unsigned word = (j & 2) ? wbt2[r].y : wbt2[r].x;
                unsigned bit = (word >> ((j & 1) * 16 + lc)) & 1u;
                stg[(lg * 4 + r) * 516 + wv * 64 + j * 16 + lc] =
                    bit ? acc[i][j][r] * inv[r] : 0.0f;
            }
        }
        __syncthreads();
#pragma unroll
        for (int it = 0; it < 4; ++it) {
            int f = it * 512 + t;
            int ml = f >> 7;
            int s4 = (f & 127) * 4;
            float4 v = *(const float4*)(stg + ml * 516 + s4);
            *(float4*)(out + ((size_t)(b * MAXLEN + m0 + i * 16 + ml)) * SEQ + s4) = v;
        }
        __syncthreads();
    }
}

// ================= launch =================

extern "C" void kernel_launch(void* const* d_in, const int* in_sizes, int n_in,
                              void* d_out, int out_size, void* d_ws, size_t ws_size,
                              hipStream_t stream) {
    const float* Mg = (const float*)d_in[0];
    const float* Wg = (const float*)d_in[1];
    // d_in[2] = lengths (unused by reference)
    const int* eb = (const int*)d_in[3];
    const int* eu = (const int*)d_in[4];
    const int* ev = (const int*)d_in[5];
    const int E = in_sizes[3];

    float* out = (float*)d_out;
    unsigned int* bits = (unsigned int*)d_ws;
    const size_t MBF_OFF = 2097152;                       // 2 MB bitmap first
    const size_t WBF_OFF = MBF_OFF + 33554432;            // + 32 MB Mbf
    const size_t NEED    = WBF_OFF + 524288;              // + 0.5 MB Wbf

    hipMemsetAsync(bits, 0, (size_t)BATCH * MAXLEN * 16 * sizeof(unsigned int), stream);

    if (ws_size >= NEED) {
        unsigned short* Mbf = (unsigned short*)((char*)d_ws + MBF_OFF);
        unsigned short* Wbf = (unsigned short*)((char*)d_ws + WBF_OFF);
        prep<<<10880, 256, 0, stream>>>(Mg, Wg, eb, eu, ev, Mbf, Wbf, bits, E);
        fused_attn_p<<<512, 512, 0, stream>>>(Mbf, Wbf, bits, out);
    } else {
        unsigned short* Wbf = (unsigned short*)((char*)d_ws + MBF_OFF);
        edge_scatter<<<(E + 255) / 256, 256, 0, stream>>>(eb, eu, ev, bits, E);
        cvt_w<<<128, 256, 0, stream>>>(Wg, Wbf);
        fused_attn<<<512, 512, 0, stream>>>(Mg, Wbf, bits, out);
    }
}